// Round 8
// baseline (298.434 us; speedup 1.0000x reference)
//
#include <hip/hip_runtime.h>
#include <hip/hip_bf16.h>
#include <stdint.h>

#define T_TOK 2048
#define HDIM  1024
#define IDIM  768
#define NEXP  32
#define TOPK  4
#define NPAIR (T_TOK*TOPK)   // 8192
#define MTILE 384
#define MAXMT 64

typedef __attribute__((ext_vector_type(8))) short bf16x8;
typedef __attribute__((ext_vector_type(4))) float f32x4;

__device__ __forceinline__ unsigned short f2bf(float f){
  union { float f; unsigned u; } v; v.f = f;
  unsigned r = (v.u + 0x7fffu + ((v.u >> 16) & 1u)) >> 16;  // RNE
  return (unsigned short)r;
}

__device__ __forceinline__ unsigned pack_bf2(float lo, float hi){
  __hip_bfloat162 h2 = __float22bfloat162_rn(float2{lo, hi});  // v_cvt_pk_bf16_f32
  union { __hip_bfloat162 h; unsigned u; } v; v.h = h2;
  return v.u;
}

// ---------------- x fp32 -> bf16 ----------------
__global__ __launch_bounds__(256) void k_convert_x(const float* __restrict__ x,
                                                   ushort* __restrict__ xb){
  int idx = blockIdx.x*256 + threadIdx.x;
  float4 v = ((const float4*)x)[idx];
  ushort4 o; o.x=f2bf(v.x); o.y=f2bf(v.y); o.z=f2bf(v.z); o.w=f2bf(v.w);
  ((ushort4*)xb)[idx] = o;
}

// ---------------- router ----------------
__global__ __launch_bounds__(256) void k_router(const float* __restrict__ x,
                                                const float* __restrict__ gw,
                                                int* __restrict__ ei, float* __restrict__ wv,
                                                int* __restrict__ counts){
  int wid  = threadIdx.x >> 6;
  int lane = threadIdx.x & 63;
  int t = blockIdx.x*4 + wid;
  float xv[16];
  #pragma unroll
  for (int i=0;i<16;i++) xv[i] = x[t*HDIM + i*64 + lane];
  float p[NEXP];
  #pragma unroll
  for (int e=0;e<NEXP;e++){
    const float* w = gw + e*HDIM;
    float a = 0.f;
    #pragma unroll
    for (int i=0;i<16;i++) a = fmaf(xv[i], w[i*64+lane], a);
    #pragma unroll
    for (int off=32; off>=1; off>>=1) a += __shfl_xor(a, off, 64);
    p[e] = a;
  }
  float m = p[0];
  #pragma unroll
  for (int e=1;e<NEXP;e++) m = fmaxf(m, p[e]);
  #pragma unroll
  for (int e=0;e<NEXP;e++) p[e] = __expf(p[e]-m);
  unsigned used = 0; int sel[TOPK]; float sw[TOPK]; float wsum = 0.f;
  #pragma unroll
  for (int k=0;k<TOPK;k++){
    float best = -1.f; int bi = 0;
    #pragma unroll
    for (int e=0;e<NEXP;e++){
      bool ok = (((used>>e)&1u)==0u) && (p[e] > best);
      best = ok ? p[e] : best; bi = ok ? e : bi;
    }
    used |= 1u<<bi; sel[k]=bi; sw[k]=best; wsum += best;
  }
  if (lane==0){
    float inv = 1.f/wsum;
    #pragma unroll
    for (int k=0;k<TOPK;k++){
      ei[t*TOPK+k] = sel[k];
      wv[t*TOPK+k] = sw[k]*inv;
      atomicAdd(&counts[sel[k]], 1);
    }
  }
}

// ---------------- offsets + m-tile worklist ----------------
__global__ void k_offsets(const int* __restrict__ counts, int* __restrict__ offsets,
                          int* __restrict__ mtE, int* __restrict__ mtM0,
                          int* __restrict__ nmt){
  if (threadIdx.x==0 && blockIdx.x==0){
    int s=0;
    for (int e=0;e<NEXP;e++){ offsets[e]=s; s+=counts[e]; }
    offsets[NEXP]=s;
    int nm=0;
    for (int e=0;e<NEXP;e++){
      int ne = counts[e];
      for (int m0=0; m0<ne && nm<MAXMT; m0+=MTILE){ mtE[nm]=e; mtM0[nm]=m0; nm++; }
    }
    nmt[0]=nm;
  }
}

__global__ __launch_bounds__(256) void k_scatter(const int* __restrict__ ei,
                                                 const int* __restrict__ offsets,
                                                 int* __restrict__ cursor,
                                                 int* __restrict__ slot_tk,
                                                 int* __restrict__ tk_slot){
  int g = blockIdx.x*256 + threadIdx.x;
  int e = ei[g];
  int pos = atomicAdd(&cursor[e], 1);
  int slot = offsets[e] + pos;
  slot_tk[slot] = g;
  tk_slot[g] = slot;
}

// ---------------- gate+up GEMM + SiLU ----------------
// M=384 x N=32 (x2 mats), K=1024 = 4 macros x 256.
// B: per-wave 1-KB lane-contiguous row-chunk loads (8 float4/thread) -> bf16 LDS,
//    padded rows (264 ushorts) -> conflict-free. 2 barriers/macro.
// A: per-lane direct-global bf16x8 frags (L2-resident xb).
__global__ __launch_bounds__(512,4) void k_gateup(const ushort* __restrict__ xb,
    const float* __restrict__ w1, const float* __restrict__ w3,
    const int* __restrict__ offsets, const int* __restrict__ slot_tk,
    const int* __restrict__ mtE, const int* __restrict__ mtM0, const int* __restrict__ nmt,
    ushort* __restrict__ act){
  int bi  = blockIdx.x;               // 1536
  int xcd = bi & 7, j = bi >> 3;      // j 0..191
  int mti = (j/24)*8 + xcd;
  int it  = j % 24;
  if (mti >= nmt[0]) return;
  int e    = mtE[mti];
  int m0   = mtM0[mti];
  int off0 = offsets[e];
  int ne   = offsets[e+1]-off0;
  int ibase = it*32;

  __shared__ ushort Bls[2][64][264];   // [buf][mat*32+row][k bf16, 264=256+8 pad]
  __shared__ int toks[MTILE];

  int tid = threadIdx.x, wid = tid>>6, lane = tid&63;
  if (tid < MTILE){
    int slot = off0 + m0 + tid;
    int fb = slot_tk[off0] >> 2;
    toks[tid] = (m0 + tid < ne) ? (slot_tk[slot] >> 2) : fb;
  }
  __syncthreads();

  // B sources: wave w owns LDS pairs p = w*8+s (mat = w>=4, row0 = (w&3)*8)
  const float* wsrc = (wid < 4 ? w1 : w3) + (size_t)e*IDIM*HDIM;
  int row0 = (wid&3)*8;
  const float* bsrc = wsrc + (size_t)(ibase+row0)*HDIM + lane*4;
  int pbase = wid*8;

  // A row pointers (3 m-frags of 16 rows, 48 rows/wave)
  const ushort* arow[3];
  #pragma unroll
  for (int m=0;m<3;m++){
    int row = wid*48 + m*16 + (lane&15);
    arow[m] = xb + (size_t)toks[row]*HDIM + (lane>>4)*8;
  }

  f32x4 accg[3][2], accu[3][2];
  #pragma unroll
  for (int m=0;m<3;m++)
    #pragma unroll
    for (int n=0;n<2;n++){ accg[m][n]=(f32x4){0,0,0,0}; accu[m][n]=(f32x4){0,0,0,0}; }

  float4 breg[8];
  auto loadB = [&](int t){
    #pragma unroll
    for (int s=0;s<8;s++) breg[s] = *(const float4*)(bsrc + (size_t)s*HDIM + t*256);
  };
  auto writeB = [&](int buf){
    #pragma unroll
    for (int s=0;s<8;s++){
      uint2 u; u.x = pack_bf2(breg[s].x, breg[s].y); u.y = pack_bf2(breg[s].z, breg[s].w);
      *(uint2*)(&Bls[buf][pbase+s][lane*4]) = u;
    }
  };
  auto compute = [&](int buf, int t){
    #pragma unroll
    for (int kk=0;kk<8;kk++){
      bf16x8 af[3];
      #pragma unroll
      for (int m=0;m<3;m++)
        af[m] = *(const bf16x8*)(arow[m] + t*256 + kk*32);
      #pragma unroll
      for (int nf=0;nf<2;nf++){
        int p = nf*16 + (lane&15);
        bf16x8 bg = *(const bf16x8*)(&Bls[buf][p   ][kk*32 + (lane>>4)*8]);
        bf16x8 bu = *(const bf16x8*)(&Bls[buf][p+32][kk*32 + (lane>>4)*8]);
        #pragma unroll
        for (int m=0;m<3;m++){
          accg[m][nf] = __builtin_amdgcn_mfma_f32_16x16x32_bf16(af[m], bg, accg[m][nf], 0,0,0);
          accu[m][nf] = __builtin_amdgcn_mfma_f32_16x16x32_bf16(af[m], bu, accu[m][nf], 0,0,0);
        }
      }
    }
  };

  loadB(0); writeB(0); __syncthreads();
  #pragma unroll 1
  for (int t=0; t<4; ++t){
    if (t < 3) loadB(t+1);             // full-macro prefetch, in flight across compute
    compute(t&1, t);
    __syncthreads();
    if (t < 3){ writeB((t+1)&1); __syncthreads(); }
  }

  int nval = ne - m0; if (nval > MTILE) nval = MTILE;
  #pragma unroll
  for (int m=0;m<3;m++)
    #pragma unroll
    for (int nf=0;nf<2;nf++)
      #pragma unroll
      for (int r=0;r<4;r++){
        int row = wid*48 + m*16 + (lane>>4)*4 + r;
        if (row < nval){
          float g = accg[m][nf][r], u = accu[m][nf][r];
          float sval = g / (1.f + __expf(-g)) * u;
          act[(size_t)(off0+m0+row)*IDIM + ibase + nf*16 + (lane&15)] = f2bf(sval);
        }
      }
}

// ---------------- down GEMM ----------------
// M=384 x N=32, K=768 = 3 macros x 256. Same streaming structure.
__global__ __launch_bounds__(512,4) void k_down(const ushort* __restrict__ act,
    const float* __restrict__ w2, const int* __restrict__ offsets,
    const int* __restrict__ mtE, const int* __restrict__ mtM0, const int* __restrict__ nmt,
    float* __restrict__ pout){
  int bi  = blockIdx.x;               // 2048
  int xcd = bi & 7, j = bi >> 3;      // j 0..255
  int mti = (j/32)*8 + xcd;
  int ht  = j % 32;
  if (mti >= nmt[0]) return;
  int e    = mtE[mti];
  int m0   = mtM0[mti];
  int off0 = offsets[e], ne = offsets[e+1]-off0;
  int hbase = ht*32;

  __shared__ ushort Bls[2][32][264];

  int tid = threadIdx.x, wid = tid>>6, lane = tid&63;

  // B sources: wave w owns rows p = w*4+s
  int row0 = wid*4;
  const float* bsrc = w2 + (size_t)e*HDIM*IDIM + (size_t)(hbase+row0)*IDIM + lane*4;
  int pbase = wid*4;

  const ushort* arow[3];
  #pragma unroll
  for (int m=0;m<3;m++){
    int row = m0 + wid*48 + m*16 + (lane&15);
    row = (row < ne) ? row : (ne-1);
    arow[m] = act + (size_t)(off0+row)*IDIM + (lane>>4)*8;
  }

  f32x4 acc[3][2];
  #pragma unroll
  for (int m=0;m<3;m++)
    #pragma unroll
    for (int n=0;n<2;n++) acc[m][n]=(f32x4){0,0,0,0};

  float4 breg[4];
  auto loadB = [&](int t){
    #pragma unroll
    for (int s=0;s<4;s++) breg[s] = *(const float4*)(bsrc + (size_t)s*IDIM + t*256);
  };
  auto writeB = [&](int buf){
    #pragma unroll
    for (int s=0;s<4;s++){
      uint2 u; u.x = pack_bf2(breg[s].x, breg[s].y); u.y = pack_bf2(breg[s].z, breg[s].w);
      *(uint2*)(&Bls[buf][pbase+s][lane*4]) = u;
    }
  };
  auto compute = [&](int buf, int t){
    #pragma unroll
    for (int kk=0;kk<8;kk++){
      bf16x8 af[3];
      #pragma unroll
      for (int m=0;m<3;m++)
        af[m] = *(const bf16x8*)(arow[m] + t*256 + kk*32);
      #pragma unroll
      for (int nf=0;nf<2;nf++){
        bf16x8 bw = *(const bf16x8*)(&Bls[buf][nf*16 + (lane&15)][kk*32 + (lane>>4)*8]);
        #pragma unroll
        for (int m=0;m<3;m++)
          acc[m][nf] = __builtin_amdgcn_mfma_f32_16x16x32_bf16(af[m], bw, acc[m][nf], 0,0,0);
      }
    }
  };

  loadB(0); writeB(0); __syncthreads();
  #pragma unroll 1
  for (int t=0; t<3; ++t){
    if (t < 2) loadB(t+1);
    compute(t&1, t);
    __syncthreads();
    if (t < 2){ writeB((t+1)&1); __syncthreads(); }
  }

  int nval = ne - m0; if (nval > MTILE) nval = MTILE;
  #pragma unroll
  for (int m=0;m<3;m++)
    #pragma unroll
    for (int nf=0;nf<2;nf++)
      #pragma unroll
      for (int r=0;r<4;r++){
        int row = wid*48 + m*16 + (lane>>4)*4 + r;
        if (row < nval)
          pout[(size_t)(off0+m0+row)*HDIM + hbase + nf*16 + (lane&15)] = acc[m][nf][r];
      }
}

// ---------------- combine ----------------
__global__ __launch_bounds__(256) void k_combine(const float* __restrict__ pout,
    const int* __restrict__ tk_slot, const float* __restrict__ wv,
    float* __restrict__ out){
  int t = blockIdx.x;
  int c = threadIdx.x;
  float a0=0,a1=0,a2=0,a3=0;
  #pragma unroll
  for (int k=0;k<TOPK;k++){
    int slot = tk_slot[t*TOPK+k];
    float w  = wv[t*TOPK+k];
    float4 v = *(const float4*)(pout + (size_t)slot*HDIM + c*4);
    a0 = fmaf(w, v.x, a0); a1 = fmaf(w, v.y, a1);
    a2 = fmaf(w, v.z, a2); a3 = fmaf(w, v.w, a3);
  }
  float4 o; o.x=a0; o.y=a1; o.z=a2; o.w=a3;
  *(float4*)(out + (size_t)t*HDIM + c*4) = o;
}

extern "C" void kernel_launch(void* const* d_in, const int* in_sizes, int n_in,
                              void* d_out, int out_size, void* d_ws, size_t ws_size,
                              hipStream_t stream){
  const float* x  = (const float*)d_in[0];
  const float* gw = (const float*)d_in[1];
  const float* w1 = (const float*)d_in[2];
  const float* w3 = (const float*)d_in[3];
  const float* w2 = (const float*)d_in[4];
  float* out = (float*)d_out;

  char* ws = (char*)d_ws;
  size_t off = 0;
  ushort* xb   = (ushort*)(ws + off); off += (size_t)T_TOK*HDIM*2;
  ushort* act  = (ushort*)(ws + off); off += (size_t)NPAIR*IDIM*2;
  float*  pout = (float*) (ws + off); off += (size_t)NPAIR*HDIM*4;
  int* counts  = (int*)(ws + off); off += NEXP*4;
  int* cursor  = (int*)(ws + off); off += NEXP*4;
  int* offsets = (int*)(ws + off); off += (NEXP+1)*4;
  int* mtE     = (int*)(ws + off); off += MAXMT*4;
  int* mtM0    = (int*)(ws + off); off += MAXMT*4;
  int* nmt     = (int*)(ws + off); off += 4;
  off = (off + 255) & ~(size_t)255;
  int*   ei      = (int*)  (ws + off); off += (size_t)NPAIR*4;
  float* wvp     = (float*)(ws + off); off += (size_t)NPAIR*4;
  int*   slot_tk = (int*)  (ws + off); off += (size_t)NPAIR*4;
  int*   tk_slot = (int*)  (ws + off); off += (size_t)NPAIR*4;

  hipMemsetAsync(counts, 0, 2*NEXP*4, stream);

  k_convert_x<<<T_TOK*HDIM/1024, 256, 0, stream>>>(x, xb);
  k_router<<<T_TOK/4, 256, 0, stream>>>(x, gw, ei, wvp, counts);
  k_offsets<<<1, 64, 0, stream>>>(counts, offsets, mtE, mtM0, nmt);
  k_scatter<<<NPAIR/256, 256, 0, stream>>>(ei, offsets, cursor, slot_tk, tk_slot);
  k_gateup<<<1536, 512, 0, stream>>>(xb, w1, w3, offsets, slot_tk, mtE, mtM0, nmt, act);
  k_down<<<2048, 512, 0, stream>>>(act, w2, offsets, mtE, mtM0, nmt, pout);
  k_combine<<<T_TOK, 256, 0, stream>>>(pout, tk_slot, wvp, out);
}

// Round 9
// 237.985 us; speedup vs baseline: 1.2540x; 1.2540x over previous
//
#include <hip/hip_runtime.h>
#include <hip/hip_bf16.h>
#include <stdint.h>

#define T_TOK 2048
#define HDIM  1024
#define IDIM  768
#define NEXP  32
#define TOPK  4
#define NPAIR (T_TOK*TOPK)   // 8192
#define MTILE 384
#define MAXMT 64

typedef __attribute__((ext_vector_type(8))) short bf16x8;
typedef __attribute__((ext_vector_type(4))) float f32x4;

#define SBAR0() __builtin_amdgcn_sched_barrier(0)
// raw barrier: drain LDS writes only, never vmcnt
#define LBAR()  do{ asm volatile("s_waitcnt lgkmcnt(0)" ::: "memory"); \
                    __builtin_amdgcn_s_barrier(); SBAR0(); }while(0)

__device__ __forceinline__ unsigned short f2bf(float f){
  union { float f; unsigned u; } v; v.f = f;
  unsigned r = (v.u + 0x7fffu + ((v.u >> 16) & 1u)) >> 16;  // RNE
  return (unsigned short)r;
}

__device__ __forceinline__ unsigned pack_bf2(float lo, float hi){
  __hip_bfloat162 h2 = __float22bfloat162_rn(float2{lo, hi});  // v_cvt_pk_bf16_f32
  union { __hip_bfloat162 h; unsigned u; } v; v.h = h2;
  return v.u;
}

// ---------------- x fp32 -> bf16 ----------------
__global__ __launch_bounds__(256) void k_convert_x(const float* __restrict__ x,
                                                   ushort* __restrict__ xb){
  int idx = blockIdx.x*256 + threadIdx.x;
  float4 v = ((const float4*)x)[idx];
  ushort4 o; o.x=f2bf(v.x); o.y=f2bf(v.y); o.z=f2bf(v.z); o.w=f2bf(v.w);
  ((ushort4*)xb)[idx] = o;
}

// ---------------- router ----------------
__global__ __launch_bounds__(256) void k_router(const float* __restrict__ x,
                                                const float* __restrict__ gw,
                                                int* __restrict__ ei, float* __restrict__ wv,
                                                int* __restrict__ counts){
  int wid  = threadIdx.x >> 6;
  int lane = threadIdx.x & 63;
  int t = blockIdx.x*4 + wid;
  float xv[16];
  #pragma unroll
  for (int i=0;i<16;i++) xv[i] = x[t*HDIM + i*64 + lane];
  float p[NEXP];
  #pragma unroll
  for (int e=0;e<NEXP;e++){
    const float* w = gw + e*HDIM;
    float a = 0.f;
    #pragma unroll
    for (int i=0;i<16;i++) a = fmaf(xv[i], w[i*64+lane], a);
    #pragma unroll
    for (int off=32; off>=1; off>>=1) a += __shfl_xor(a, off, 64);
    p[e] = a;
  }
  float m = p[0];
  #pragma unroll
  for (int e=1;e<NEXP;e++) m = fmaxf(m, p[e]);
  #pragma unroll
  for (int e=0;e<NEXP;e++) p[e] = __expf(p[e]-m);
  unsigned used = 0; int sel[TOPK]; float sw[TOPK]; float wsum = 0.f;
  #pragma unroll
  for (int k=0;k<TOPK;k++){
    float best = -1.f; int bi = 0;
    #pragma unroll
    for (int e=0;e<NEXP;e++){
      bool ok = (((used>>e)&1u)==0u) && (p[e] > best);
      best = ok ? p[e] : best; bi = ok ? e : bi;
    }
    used |= 1u<<bi; sel[k]=bi; sw[k]=best; wsum += best;
  }
  if (lane==0){
    float inv = 1.f/wsum;
    #pragma unroll
    for (int k=0;k<TOPK;k++){
      ei[t*TOPK+k] = sel[k];
      wv[t*TOPK+k] = sw[k]*inv;
      atomicAdd(&counts[sel[k]], 1);
    }
  }
}

// ---------------- offsets + m-tile worklist ----------------
__global__ void k_offsets(const int* __restrict__ counts, int* __restrict__ offsets,
                          int* __restrict__ mtE, int* __restrict__ mtM0,
                          int* __restrict__ nmt){
  if (threadIdx.x==0 && blockIdx.x==0){
    int s=0;
    for (int e=0;e<NEXP;e++){ offsets[e]=s; s+=counts[e]; }
    offsets[NEXP]=s;
    int nm=0;
    for (int e=0;e<NEXP;e++){
      int ne = counts[e];
      for (int m0=0; m0<ne && nm<MAXMT; m0+=MTILE){ mtE[nm]=e; mtM0[nm]=m0; nm++; }
    }
    nmt[0]=nm;
  }
}

__global__ __launch_bounds__(256) void k_scatter(const int* __restrict__ ei,
                                                 const int* __restrict__ offsets,
                                                 int* __restrict__ cursor,
                                                 int* __restrict__ slot_tk,
                                                 int* __restrict__ tk_slot){
  int g = blockIdx.x*256 + threadIdx.x;
  int e = ei[g];
  int pos = atomicAdd(&cursor[e], 1);
  int slot = offsets[e] + pos;
  slot_tk[slot] = g;
  tk_slot[g] = slot;
}

// ---------------- gate+up GEMM + SiLU ----------------
// M=384 x N=32 (x2 mats). K split into NH=8 steps of 128.
// Per step: A(h) preloaded in regs (L2; issued BEFORE any younger HBM load),
// B(h+1) fp32 HBM stream in flight across compute (FIFO-safe: issued last),
// one raw s_barrier per step, lgkmcnt-only drain.
__global__ __launch_bounds__(512,3) void k_gateup(const ushort* __restrict__ xb,
    const float* __restrict__ w1, const float* __restrict__ w3,
    const int* __restrict__ offsets, const int* __restrict__ slot_tk,
    const int* __restrict__ mtE, const int* __restrict__ mtM0, const int* __restrict__ nmt,
    ushort* __restrict__ act){
  const int NH = 8;
  int bi  = blockIdx.x;               // 1536
  int xcd = bi & 7, j = bi >> 3;      // j 0..191
  int mti = (j/24)*8 + xcd;
  int it  = j % 24;
  if (mti >= nmt[0]) return;
  int e    = mtE[mti];
  int m0   = mtM0[mti];
  int off0 = offsets[e];
  int ne   = offsets[e+1]-off0;
  int ibase = it*32;

  __shared__ ushort Bls[2][64][136];   // [buf][mat*32+row][128 bf16 + 8 pad]
  __shared__ int toks[MTILE];

  int tid = threadIdx.x, wid = tid>>6, lane = tid&63;
  if (tid < MTILE){
    int slot = off0 + m0 + tid;
    int fb = slot_tk[off0] >> 2;
    toks[tid] = (m0 + tid < ne) ? (slot_tk[slot] >> 2) : fb;
  }
  __syncthreads();

  // B staging: 64 rows x 128 f32 per step; 4 rounds of 512 threads x 16 B.
  const float* bp[4]; int brow_s[4];
  #pragma unroll
  for (int s=0;s<4;s++){
    int row = s*16 + wid*2 + (lane>>5);   // 0..63
    brow_s[s] = row;
    int mat = row>>5, ir = row&31;
    bp[s] = (mat ? w3 : w1) + (size_t)e*IDIM*HDIM
          + (size_t)(ibase+ir)*HDIM + (lane&31)*4;
  }
  // A row pointers (3 m-frags of 16 rows; 48 rows/wave)
  int q = lane>>4;
  const ushort* arow[3];
  #pragma unroll
  for (int m=0;m<3;m++){
    int row = wid*48 + m*16 + (lane&15);
    arow[m] = xb + (size_t)toks[row]*HDIM + q*8;
  }

  f32x4 accg[3][2], accu[3][2];
  #pragma unroll
  for (int m=0;m<3;m++)
    #pragma unroll
    for (int n=0;n<2;n++){ accg[m][n]=(f32x4){0,0,0,0}; accu[m][n]=(f32x4){0,0,0,0}; }

  float4 breg[4];
  bf16x8 aA[3][4];

  auto loadB = [&](int t){
    #pragma unroll
    for (int s=0;s<4;s++) breg[s] = *(const float4*)(bp[s] + t*128);
  };
  auto writeB = [&](int buf){
    #pragma unroll
    for (int s=0;s<4;s++){
      uint2 u; u.x = pack_bf2(breg[s].x, breg[s].y); u.y = pack_bf2(breg[s].z, breg[s].w);
      *(uint2*)(&Bls[buf][brow_s[s]][(lane&31)*4]) = u;
    }
  };
  auto loadA = [&](int t){
    #pragma unroll
    for (int m=0;m<3;m++)
      #pragma unroll
      for (int kk=0;kk<4;kk++)
        aA[m][kk] = *(const bf16x8*)(arow[m] + t*128 + kk*32);
  };
  auto compute = [&](int buf){
    #pragma unroll
    for (int kk=0;kk<4;kk++){
      #pragma unroll
      for (int nf=0;nf<2;nf++){
        bf16x8 bg = *(const bf16x8*)(&Bls[buf][     nf*16 + (lane&15)][kk*32 + q*8]);
        bf16x8 bu = *(const bf16x8*)(&Bls[buf][32 + nf*16 + (lane&15)][kk*32 + q*8]);
        #pragma unroll
        for (int m=0;m<3;m++){
          accg[m][nf] = __builtin_amdgcn_mfma_f32_16x16x32_bf16(aA[m][kk], bg, accg[m][nf], 0,0,0);
          accu[m][nf] = __builtin_amdgcn_mfma_f32_16x16x32_bf16(aA[m][kk], bu, accu[m][nf], 0,0,0);
        }
      }
    }
  };

  // prologue: LDS0 = B(0); issue A(0) THEN B(1) (A older than HBM stream)
  loadB(0);
  writeB(0);                 // compiler inserts vmcnt wait for breg
  loadA(0);
  SBAR0();
  loadB(1);
  LBAR();

  #pragma unroll 2
  for (int h=0; h<NH; ++h){
    compute(h&1);            // waits only A(h): vmcnt(#B in flight)
    if (h+1 < NH){
      writeB((h+1)&1);       // B(h+1) has had full compute to land
      loadA(h+1);            // issue A before next B (FIFO order)
      SBAR0();
      if (h+2 < NH) loadB(h+2);
      LBAR();
    }
  }

  int nval = ne - m0; if (nval > MTILE) nval = MTILE;
  #pragma unroll
  for (int m=0;m<3;m++)
    #pragma unroll
    for (int nf=0;nf<2;nf++)
      #pragma unroll
      for (int r=0;r<4;r++){
        int row = wid*48 + m*16 + (lane>>4)*4 + r;
        if (row < nval){
          float g = accg[m][nf][r], u = accu[m][nf][r];
          float sval = g / (1.f + __expf(-g)) * u;
          act[(size_t)(off0+m0+row)*IDIM + ibase + nf*16 + (lane&15)] = f2bf(sval);
        }
      }
}

// ---------------- down GEMM ----------------
// M=384 x N=64, K=768 = 6 steps of 128. Same pipeline.
__global__ __launch_bounds__(512,3) void k_down(const ushort* __restrict__ act,
    const float* __restrict__ w2, const int* __restrict__ offsets,
    const int* __restrict__ mtE, const int* __restrict__ mtM0, const int* __restrict__ nmt,
    float* __restrict__ pout){
  const int NH = 6;
  int bi  = blockIdx.x;               // 1024
  int xcd = bi & 7, j = bi >> 3;      // j 0..127
  int mti = (j>>4)*8 + xcd;
  int ht  = j & 15;
  if (mti >= nmt[0]) return;
  int e    = mtE[mti];
  int m0   = mtM0[mti];
  int off0 = offsets[e], ne = offsets[e+1]-off0;
  int hbase = ht*64;

  __shared__ ushort Bls[2][64][136];

  int tid = threadIdx.x, wid = tid>>6, lane = tid&63;

  const float* bp[4]; int brow_s[4];
  #pragma unroll
  for (int s=0;s<4;s++){
    int row = s*16 + wid*2 + (lane>>5);   // 0..63
    brow_s[s] = row;
    bp[s] = w2 + (size_t)e*HDIM*IDIM + (size_t)(hbase+row)*IDIM + (lane&31)*4;
  }
  int q = lane>>4;
  const ushort* arow[3];
  #pragma unroll
  for (int m=0;m<3;m++){
    int row = m0 + wid*48 + m*16 + (lane&15);
    row = (row < ne) ? row : (ne-1);
    arow[m] = act + (size_t)(off0+row)*IDIM + q*8;
  }

  f32x4 acc[3][4];
  #pragma unroll
  for (int m=0;m<3;m++)
    #pragma unroll
    for (int n=0;n<4;n++) acc[m][n]=(f32x4){0,0,0,0};

  float4 breg[4];
  bf16x8 aA[3][4];

  auto loadB = [&](int t){
    #pragma unroll
    for (int s=0;s<4;s++) breg[s] = *(const float4*)(bp[s] + t*128);
  };
  auto writeB = [&](int buf){
    #pragma unroll
    for (int s=0;s<4;s++){
      uint2 u; u.x = pack_bf2(breg[s].x, breg[s].y); u.y = pack_bf2(breg[s].z, breg[s].w);
      *(uint2*)(&Bls[buf][brow_s[s]][(lane&31)*4]) = u;
    }
  };
  auto loadA = [&](int t){
    #pragma unroll
    for (int m=0;m<3;m++)
      #pragma unroll
      for (int kk=0;kk<4;kk++)
        aA[m][kk] = *(const bf16x8*)(arow[m] + t*128 + kk*32);
  };
  auto compute = [&](int buf){
    #pragma unroll
    for (int kk=0;kk<4;kk++){
      #pragma unroll
      for (int nf=0;nf<4;nf++){
        bf16x8 bw = *(const bf16x8*)(&Bls[buf][nf*16 + (lane&15)][kk*32 + q*8]);
        #pragma unroll
        for (int m=0;m<3;m++)
          acc[m][nf] = __builtin_amdgcn_mfma_f32_16x16x32_bf16(aA[m][kk], bw, acc[m][nf], 0,0,0);
      }
    }
  };

  loadB(0);
  writeB(0);
  loadA(0);
  SBAR0();
  loadB(1);
  LBAR();

  #pragma unroll 2
  for (int h=0; h<NH; ++h){
    compute(h&1);
    if (h+1 < NH){
      writeB((h+1)&1);
      loadA(h+1);
      SBAR0();
      if (h+2 < NH) loadB(h+2);
      LBAR();
    }
  }

  int nval = ne - m0; if (nval > MTILE) nval = MTILE;
  #pragma unroll
  for (int m=0;m<3;m++)
    #pragma unroll
    for (int nf=0;nf<4;nf++)
      #pragma unroll
      for (int r=0;r<4;r++){
        int row = wid*48 + m*16 + (lane>>4)*4 + r;
        if (row < nval)
          pout[(size_t)(off0+m0+row)*HDIM + hbase + nf*16 + (lane&15)] = acc[m][nf][r];
      }
}

// ---------------- combine ----------------
__global__ __launch_bounds__(256) void k_combine(const float* __restrict__ pout,
    const int* __restrict__ tk_slot, const float* __restrict__ wv,
    float* __restrict__ out){
  int t = blockIdx.x;
  int c = threadIdx.x;
  float a0=0,a1=0,a2=0,a3=0;
  #pragma unroll
  for (int k=0;k<TOPK;k++){
    int slot = tk_slot[t*TOPK+k];
    float w  = wv[t*TOPK+k];
    float4 v = *(const float4*)(pout + (size_t)slot*HDIM + c*4);
    a0 = fmaf(w, v.x, a0); a1 = fmaf(w, v.y, a1);
    a2 = fmaf(w, v.z, a2); a3 = fmaf(w, v.w, a3);
  }
  float4 o; o.x=a0; o.y=a1; o.z=a2; o.w=a3;
  *(float4*)(out + (size_t)t*HDIM + c*4) = o;
}

extern "C" void kernel_launch(void* const* d_in, const int* in_sizes, int n_in,
                              void* d_out, int out_size, void* d_ws, size_t ws_size,
                              hipStream_t stream){
  const float* x  = (const float*)d_in[0];
  const float* gw = (const float*)d_in[1];
  const float* w1 = (const float*)d_in[2];
  const float* w3 = (const float*)d_in[3];
  const float* w2 = (const float*)d_in[4];
  float* out = (float*)d_out;

  char* ws = (char*)d_ws;
  size_t off = 0;
  ushort* xb   = (ushort*)(ws + off); off += (size_t)T_TOK*HDIM*2;
  ushort* act  = (ushort*)(ws + off); off += (size_t)NPAIR*IDIM*2;
  float*  pout = (float*) (ws + off); off += (size_t)NPAIR*HDIM*4;
  int* counts  = (int*)(ws + off); off += NEXP*4;
  int* cursor  = (int*)(ws + off); off += NEXP*4;
  int* offsets = (int*)(ws + off); off += (NEXP+1)*4;
  int* mtE     = (int*)(ws + off); off += MAXMT*4;
  int* mtM0    = (int*)(ws + off); off += MAXMT*4;
  int* nmt     = (int*)(ws + off); off += 4;
  off = (off + 255) & ~(size_t)255;
  int*   ei      = (int*)  (ws + off); off += (size_t)NPAIR*4;
  float* wvp     = (float*)(ws + off); off += (size_t)NPAIR*4;
  int*   slot_tk = (int*)  (ws + off); off += (size_t)NPAIR*4;
  int*   tk_slot = (int*)  (ws + off); off += (size_t)NPAIR*4;

  hipMemsetAsync(counts, 0, 2*NEXP*4, stream);

  k_convert_x<<<T_TOK*HDIM/1024, 256, 0, stream>>>(x, xb);
  k_router<<<T_TOK/4, 256, 0, stream>>>(x, gw, ei, wvp, counts);
  k_offsets<<<1, 64, 0, stream>>>(counts, offsets, mtE, mtM0, nmt);
  k_scatter<<<NPAIR/256, 256, 0, stream>>>(ei, offsets, cursor, slot_tk, tk_slot);
  k_gateup<<<1536, 512, 0, stream>>>(xb, w1, w3, offsets, slot_tk, mtE, mtM0, nmt, act);
  k_down<<<1024, 512, 0, stream>>>(act, w2, offsets, mtE, mtM0, nmt, pout);
  k_combine<<<T_TOK, 256, 0, stream>>>(pout, tk_slot, wvp, out);
}